// Round 2
// baseline (144.262 us; speedup 1.0000x reference)
//
#include <hip/hip_runtime.h>
#include <math.h>

#define B_ 64
#define E_ 256
#define S_ 32
#define H_ 16
#define P_ 512
#define KC_ 46
#define QKV_N (B_*S_*E_)   // 524288 floats per Q/K/V region

// workspace float offsets (all float4-aligned)
#define WS_CM     0        // 64   key multiplicities
#define WS_WK     256      // 2944 Wk[64][46] per-row class weights
#define WS_INVDEN 3328     // 1
#define WS_C      3392     // 46   logit constant c[k]
#define WS_M      3584     // 11776 M[46][256] = Hw @ Wout
#define WS_WT     16384    // 196608 WT[256][768] transposed in_proj_w
#define WS_QKV    262144   // 3*524288
#define WS_OHAT   1835008  // 16384 O_hat[64][256]

// ============ K0: prep (W-transpose | pair setup | M,c | zero) =============
__global__ __launch_bounds__(128) void k_prep(
    const float* __restrict__ w, const int* __restrict__ labels0,
    const int* __restrict__ labels1, const float* __restrict__ wout,
    const float* __restrict__ bout, const float* __restrict__ fw,
    const float* __restrict__ fbi, const float* __restrict__ hw,
    const float* __restrict__ hb, float* __restrict__ ws,
    float* __restrict__ out) {
  __shared__ float sm[4608];
  const int bid = blockIdx.x, t = threadIdx.x;
  if (bid < 96) {
    // ---- transpose in_proj_w [768][256] -> WT[256][768], 8 rows/block ----
    float* WT = ws + WS_WT;
#pragma unroll
    for (int u = 0; u < 4; ++u) {
      int idx = u*128 + t;            // 0..511 f4's of this 8-row strip
      int r = idx >> 6, f = idx & 63;
      int row = bid*8 + r;
      float4 v = ((const float4*)(w + (size_t)row*E_))[f];
      WT[(f*4+0)*768 + row] = v.x;
      WT[(f*4+1)*768 + row] = v.y;
      WT[(f*4+2)*768 + row] = v.z;
      WT[(f*4+3)*768 + row] = v.w;
    }
  } else if (bid == 96) {
    // ---- pair selection, class ids, Wk, cm, inv_den ----
    float* csh = sm;                  // 64
    float* cls = sm + 64;             // 46
    float* wsh = sm + 112;            // 46
    float* den = sm + 159;            // 1
    float* Wk  = sm + 160;            // 2944
    int* scan = (int*)(sm + 3104);    // 128
    int* l0   = (int*)(sm + 3232);    // 64
    int* l1   = (int*)(sm + 3296);    // 64
    int* seli = (int*)(sm + 3360);    // 512
    int* selj = (int*)(sm + 3872);    // 512
    if (t < 64) { l0[t] = labels0[t]; l1[t] = labels1[t]; csh[t] = 0.f; }
    if (t < KC_) cls[t] = 0.f;
    if (t == 0) den[0] = 0.f;
    for (int i = t; i < 2944; i += 128) Wk[i] = 0.f;
    __syncthreads();
    unsigned bits = 0; int c = 0;
    for (int u = 0; u < 32; ++u) {    // contiguous 32-chunk keeps row-major order
      int idx = t*32 + u;
      if (l1[idx>>6] == l1[idx&63]) { bits |= 1u<<u; ++c; }
    }
    scan[t] = c; __syncthreads();
    for (int off = 1; off < 128; off <<= 1) {
      int v = (t >= off) ? scan[t-off] : 0;
      __syncthreads();
      scan[t] += v;
      __syncthreads();
    }
    const int total = scan[127];
    int rank = scan[t] - c;           // exclusive prefix
    for (int p = t; p < P_; p += 128)
      if (p >= total) { seli[p] = 0; selj[p] = 0; }   // fill_value=0
    for (int u = 0; u < 32; ++u) {
      if (bits & (1u<<u)) {
        if (rank < P_) { int idx = t*32+u; seli[rank] = idx>>6; selj[rank] = idx&63; }
        ++rank;
      }
    }
    __syncthreads();
    int ii[4], yy[4]; float vv[4];
#pragma unroll
    for (int r = 0; r < 4; ++r) {
      int p = t + r*128;
      int i = seli[p], j = selj[p];
      atomicAdd(&csh[j], 1.0f);       // multiplicity incl. padding pairs
      int la = l0[i], lb = l0[j];
      int y;
      if (la == lb) y = 0;
      else {
        int lo = la < lb ? la : lb, hi = la < lb ? lb : la;
        y = 1 + lo*9 - (lo*(lo-1))/2 + (hi-lo-1);
      }
      float v = (p < total) ? 1.f : 0.f;
      if (v > 0.f) atomicAdd(&cls[y], 1.f);
      ii[r] = i; yy[r] = y; vv[r] = v;
    }
    __syncthreads();
    if (t < KC_) {
      float cv = cls[t];
      wsh[t] = cv > 0.f ? 1.0f/cv : 0.f;
      if (cv > 0.f) atomicAdd(den, 1.0f);   // sum(wy) == #present classes
    }
    __syncthreads();
#pragma unroll
    for (int r = 0; r < 4; ++r)
      if (vv[r] > 0.f) atomicAdd(&Wk[ii[r]*KC_ + yy[r]], wsh[yy[r]]);
    __syncthreads();
    if (t < 64) ws[WS_CM + t] = csh[t];
    for (int i = t; i < 2944; i += 128) ws[WS_WK + i] = Wk[i];
    if (t == 0) ws[WS_INVDEN] = 1.0f / den[0];
  } else if (bid < 143) {
    // ---- M[k,:] = hw[k,:] @ Wout  and  c[k] ----
    int k = bid - 97;
    float* hwsh = sm;                 // 256
    float* redA = sm + 256;           // 128
    float* redB = sm + 384;           // 128
    hwsh[t]     = hw[k*E_ + t];
    hwsh[t+128] = hw[k*E_ + t + 128];
    __syncthreads();
    float a0 = 0.f, a1 = 0.f;
#pragma unroll 4
    for (int e = 0; e < E_; ++e) {
      float hv = hwsh[e];
      a0 = fmaf(hv, wout[e*E_ + t], a0);
      a1 = fmaf(hv, wout[e*E_ + t + 128], a1);
    }
    ws[WS_M + k*E_ + t] = a0;
    ws[WS_M + k*E_ + t + 128] = a1;
    redA[t] = hwsh[t] + hwsh[t+128];
    redB[t] = hwsh[t]*bout[t] + hwsh[t+128]*bout[t+128];
    __syncthreads();
    for (int off = 64; off > 0; off >>= 1) {
      if (t < off) { redA[t] += redA[t+off]; redB[t] += redB[t+off]; }
      __syncthreads();
    }
    if (t == 0) {
      float sfw = 0.f;
      for (int s = 0; s < S_; ++s) sfw += fw[s];
      ws[WS_C + k] = fbi[0]*redA[0] + sfw*redB[0] + hb[k];
    }
  } else {
    // ---- zero O_hat + d_out ----
    int zb = bid - 143;
    float4* oz = (float4*)(ws + WS_OHAT);
#pragma unroll
    for (int i = 0; i < 8; ++i)
      oz[zb*1024 + i*128 + t] = make_float4(0.f, 0.f, 0.f, 0.f);
    if (zb == 0 && t == 0) out[0] = 0.f;
  }
}

// ============ K1: QKV projection, W from global WT (VMEM), X from LDS ======
// grid (12 out-chunks, 64 b) x 64 threads; thread tile 8 out x 4 s
__global__ __launch_bounds__(64) void k_proj(
    const float* __restrict__ feat, const float* __restrict__ bias,
    float* __restrict__ ws) {
  const int cc = blockIdx.x, b = blockIdx.y, t = threadIdx.x;
  __shared__ float xs[E_*S_];
  const float4* fb4 = (const float4*)(feat + (size_t)b*(E_*S_));
  float4* xs4 = (float4*)xs;
#pragma unroll
  for (int i = 0; i < 32; ++i) xs4[i*64 + t] = fb4[i*64 + t];
  __syncthreads();
  const int to = t & 7, ts = t >> 3;
  const int out0 = cc*64 + to*8;
  const float4* WT4 = (const float4*)(ws + WS_WT);
  const int wi = cc*16 + to*2;
  float acc[8][4];
#pragma unroll
  for (int o = 0; o < 8; ++o)
#pragma unroll
    for (int si = 0; si < 4; ++si) acc[o][si] = 0.f;
#pragma unroll 4
  for (int e = 0; e < E_; ++e) {
    float4 w0 = WT4[e*192 + wi];
    float4 w1 = WT4[e*192 + wi + 1];
    float4 x4 = xs4[e*8 + ts];
    float wv[8] = {w0.x,w0.y,w0.z,w0.w,w1.x,w1.y,w1.z,w1.w};
    float xv[4] = {x4.x,x4.y,x4.z,x4.w};
#pragma unroll
    for (int o = 0; o < 8; ++o)
#pragma unroll
      for (int si = 0; si < 4; ++si)
        acc[o][si] = fmaf(wv[o], xv[si], acc[o][si]);
  }
  float4 b0 = *(const float4*)(bias + out0);
  float4 b1 = *(const float4*)(bias + out0 + 4);
  const float bb[8] = {b0.x,b0.y,b0.z,b0.w,b1.x,b1.y,b1.z,b1.w};
  const int r = out0 >> 8, e_in = out0 & 255;
  float* dst = ws + WS_QKV + (size_t)r*QKV_N + (size_t)b*(S_*E_) + e_in;
#pragma unroll
  for (int si = 0; si < 4; ++si) {
    int s = ts*4 + si;
    float4 o0 = make_float4(acc[0][si]+bb[0], acc[1][si]+bb[1],
                            acc[2][si]+bb[2], acc[3][si]+bb[3]);
    float4 o1 = make_float4(acc[4][si]+bb[4], acc[5][si]+bb[5],
                            acc[6][si]+bb[6], acc[7][si]+bb[7]);
    *(float4*)(dst + s*E_)     = o0;
    *(float4*)(dst + s*E_ + 4) = o1;
  }
}

// ============ K2: weighted attention per (s,h); O_hat += fw[s]*O ===========
__global__ __launch_bounds__(256) void k_attn(
    float* __restrict__ ws, const float* __restrict__ fw) {
  const int s = blockIdx.x >> 4, h = blockIdx.x & 15;
  const int t = threadIdx.x;
  __shared__ float qT[16*68], kT[16*68], vs[64*20];
  __shared__ float sc[64*68], pT[64*68], red[4*64*20], cm[64];
  const float* qkv = ws + WS_QKV;
  const int a = t >> 2, dq = t & 3;
  {
    size_t off = (size_t)a*(S_*E_) + (size_t)s*E_ + h*16 + dq*4;
    float4 q4 = *(const float4*)(qkv + off);
    float4 k4 = *(const float4*)(qkv + QKV_N + off);
    float4 v4 = *(const float4*)(qkv + 2*(size_t)QKV_N + off);
    qT[(dq*4+0)*68 + a] = q4.x; qT[(dq*4+1)*68 + a] = q4.y;
    qT[(dq*4+2)*68 + a] = q4.z; qT[(dq*4+3)*68 + a] = q4.w;
    kT[(dq*4+0)*68 + a] = k4.x; kT[(dq*4+1)*68 + a] = k4.y;
    kT[(dq*4+2)*68 + a] = k4.z; kT[(dq*4+3)*68 + a] = k4.w;
    *(float4*)(vs + a*20 + dq*4) = v4;
  }
  if (t < 64) cm[t] = ws[WS_CM + t];
  __syncthreads();
  // ---- scores: 4x4 register outer product ----
  const int ta = t & 15, tb = t >> 4;
  float sa[4][4];
#pragma unroll
  for (int r = 0; r < 4; ++r)
#pragma unroll
    for (int c = 0; c < 4; ++c) sa[r][c] = 0.f;
#pragma unroll
  for (int d = 0; d < 16; ++d) {
    float4 qv = *(float4*)(qT + d*68 + ta*4);
    float4 kv = *(float4*)(kT + d*68 + tb*4);
    float qr[4] = {qv.x,qv.y,qv.z,qv.w};
    float kc[4] = {kv.x,kv.y,kv.z,kv.w};
#pragma unroll
    for (int r = 0; r < 4; ++r)
#pragma unroll
      for (int c = 0; c < 4; ++c) sa[r][c] = fmaf(qr[r], kc[c], sa[r][c]);
  }
#pragma unroll
  for (int r = 0; r < 4; ++r)
    *(float4*)(sc + (ta*4+r)*68 + tb*4) =
        make_float4(sa[r][0]*0.25f, sa[r][1]*0.25f, sa[r][2]*0.25f, sa[r][3]*0.25f);
  __syncthreads();
  // ---- weighted softmax row a; thread covers b = dq*16..dq*16+15 ----
  float pv[16], cmv[16];
#pragma unroll
  for (int i4 = 0; i4 < 4; ++i4) {
    float4 v = *(float4*)(sc + a*68 + dq*16 + i4*4);
    pv[i4*4+0] = v.x; pv[i4*4+1] = v.y; pv[i4*4+2] = v.z; pv[i4*4+3] = v.w;
  }
#pragma unroll
  for (int i = 0; i < 16; ++i) cmv[i] = cm[dq*16 + i];
  float Mx = -1e30f;
#pragma unroll
  for (int i = 0; i < 16; ++i) if (cmv[i] > 0.f) Mx = fmaxf(Mx, pv[i]);
  Mx = fmaxf(Mx, __shfl_xor(Mx, 1));
  Mx = fmaxf(Mx, __shfl_xor(Mx, 2));
  float z = 0.f;
#pragma unroll
  for (int i = 0; i < 16; ++i) {
    float e = (cmv[i] > 0.f) ? cmv[i]*__expf(pv[i]-Mx) : 0.f;
    pv[i] = e; z += e;
  }
  z += __shfl_xor(z, 1);
  z += __shfl_xor(z, 2);
  float rz = 1.0f / z;
#pragma unroll
  for (int i = 0; i < 16; ++i) pT[(dq*16+i)*68 + a] = pv[i]*rz;
  __syncthreads();
  // ---- PV: split b over 4 waves, 4a x 4d register tile ----
  const int g = t >> 6, td = (t >> 4) & 3, ta2 = t & 15;
  float o[4][4];
#pragma unroll
  for (int r = 0; r < 4; ++r)
#pragma unroll
    for (int c = 0; c < 4; ++c) o[r][c] = 0.f;
#pragma unroll
  for (int i = 0; i < 16; ++i) {
    int bb = g*16 + i;
    float4 p4 = *(float4*)(pT + bb*68 + ta2*4);
    float4 v4 = *(float4*)(vs + bb*20 + td*4);
    float pr[4] = {p4.x,p4.y,p4.z,p4.w};
    float vc[4] = {v4.x,v4.y,v4.z,v4.w};
#pragma unroll
    for (int r = 0; r < 4; ++r)
#pragma unroll
      for (int c = 0; c < 4; ++c) o[r][c] = fmaf(pr[r], vc[c], o[r][c]);
  }
#pragma unroll
  for (int r = 0; r < 4; ++r)
    *(float4*)(red + g*1280 + (ta2*4+r)*20 + td*4) =
        make_float4(o[r][0], o[r][1], o[r][2], o[r][3]);
  __syncthreads();
  // ---- reduce over g, scale by fw[s], accumulate O_hat ----
  const float fwS = fw[s];
  float4 osum = make_float4(0.f, 0.f, 0.f, 0.f);
#pragma unroll
  for (int g2 = 0; g2 < 4; ++g2) {
    float4 v = *(float4*)(red + g2*1280 + a*20 + dq*4);
    osum.x += v.x; osum.y += v.y; osum.z += v.z; osum.w += v.w;
  }
  float* oh = ws + WS_OHAT + a*E_ + h*16 + dq*4;
  atomicAdd(oh+0, fwS*osum.x);
  atomicAdd(oh+1, fwS*osum.y);
  atomicAdd(oh+2, fwS*osum.z);
  atomicAdd(oh+3, fwS*osum.w);
}

// ============ K3: logits + lse + weighted-CE contribution per row ==========
__global__ __launch_bounds__(256) void k_final(
    const float* __restrict__ ws, float* __restrict__ out) {
  const int aa = blockIdx.x, t = threadIdx.x;
  __shared__ float oh[256], lg[64];
  oh[t] = ws[WS_OHAT + aa*E_ + t];
  __syncthreads();
  const int k = t >> 2, q = t & 3;
  if (k < KC_) {
    float lv = 0.f;
    const float4* M4 = (const float4*)(ws + WS_M + k*E_ + q*64);
    const float4* o4 = (const float4*)(oh + q*64);
#pragma unroll
    for (int j = 0; j < 16; ++j) {
      float4 m = M4[j], o = o4[j];
      lv = fmaf(m.x, o.x, lv); lv = fmaf(m.y, o.y, lv);
      lv = fmaf(m.z, o.z, lv); lv = fmaf(m.w, o.w, lv);
    }
    lv += __shfl_xor(lv, 1);
    lv += __shfl_xor(lv, 2);
    if (q == 0) lg[k] = lv + ws[WS_C + k];
  }
  __syncthreads();
  if (t < 64) {
    float x = (t < KC_) ? lg[t] : -1e30f;
    float Mx = x;
#pragma unroll
    for (int off = 1; off < 64; off <<= 1) Mx = fmaxf(Mx, __shfl_xor(Mx, off));
    float z = (t < KC_) ? __expf(x - Mx) : 0.f;
#pragma unroll
    for (int off = 1; off < 64; off <<= 1) z += __shfl_xor(z, off);
    float lse = Mx + __logf(z);
    float term = (t < KC_) ? ws[WS_WK + aa*KC_ + t] * (lse - x) : 0.f;
#pragma unroll
    for (int off = 1; off < 64; off <<= 1) term += __shfl_xor(term, off);
    if (t == 0) atomicAdd(out, term * ws[WS_INVDEN]);
  }
}

extern "C" void kernel_launch(void* const* d_in, const int* in_sizes, int n_in,
                              void* d_out, int out_size, void* d_ws, size_t ws_size,
                              hipStream_t stream) {
  const float* feat    = (const float*)d_in[0];
  const int*   labels0 = (const int*)d_in[1];
  const int*   labels1 = (const int*)d_in[2];
  const float* ipw     = (const float*)d_in[3];
  const float* ipb     = (const float*)d_in[4];
  const float* opw     = (const float*)d_in[5];
  const float* opb     = (const float*)d_in[6];
  const float* fw      = (const float*)d_in[7];
  const float* fbi     = (const float*)d_in[8];
  const float* hw      = (const float*)d_in[9];
  const float* hb      = (const float*)d_in[10];
  float* out = (float*)d_out;
  float* ws  = (float*)d_ws;

  k_prep<<<147, 128, 0, stream>>>(ipw, labels0, labels1, opw, opb, fw, fbi,
                                  hw, hb, ws, out);
  k_proj<<<dim3(12, 64), 64, 0, stream>>>(feat, ipb, ws);
  k_attn<<<512, 256, 0, stream>>>(ws, fw);
  k_final<<<64, 256, 0, stream>>>(ws, out);
}

// Round 3
// 126.916 us; speedup vs baseline: 1.1367x; 1.1367x over previous
//
#include <hip/hip_runtime.h>
#include <math.h>

#define B_ 64
#define E_ 256
#define S_ 32
#define H_ 16
#define P_ 512
#define KC_ 46
#define QKV_N (B_*S_*E_)   // 524288 floats per Q/K/V region

// workspace float offsets (float4-aligned)
#define WS_CM     0        // 64    key multiplicities
#define WS_WK     256      // 2944  Wk[64][46] per-row class weights
#define WS_INVDEN 3328     // 1
#define WS_C      3392     // 46    logit constant c[k]
#define WS_M      3584     // 11776 M[46][256] = Hw @ Wout
#define WS_WT     16384    // 196608 WT[256][768] transposed in_proj_w
#define WS_QKV    262144   // 3*524288
#define WS_OPART  1835008  // 524288 O_part[32][16][64][16]  (s,h,a,d)

// ============ K0: prep (WT transpose | pair setup | M,c | zero out) ========
__global__ __launch_bounds__(256) void k_prep(
    const float* __restrict__ w, const int* __restrict__ labels0,
    const int* __restrict__ labels1, const float* __restrict__ wout,
    const float* __restrict__ bout, const float* __restrict__ fw,
    const float* __restrict__ fbi, const float* __restrict__ hw,
    const float* __restrict__ hb, float* __restrict__ ws,
    float* __restrict__ out) {
  __shared__ float sm[8192];
  const int bid = blockIdx.x, t = threadIdx.x;
  if (bid < 48) {
    // ---- transpose in_proj_w [768][256] -> WT[256][768], 64x64 LDS tile ---
    const int r0 = (bid >> 2) * 64, c0 = (bid & 3) * 64;
    float* ts = sm;                               // 64 x 65
#pragma unroll
    for (int p = 0; p < 4; ++p) {
      int r = p*16 + (t >> 4), c4 = t & 15;
      float4 v = *(const float4*)(w + (size_t)(r0+r)*E_ + c0 + c4*4);
      ts[(c4*4+0)*65 + r] = v.x;
      ts[(c4*4+1)*65 + r] = v.y;
      ts[(c4*4+2)*65 + r] = v.z;
      ts[(c4*4+3)*65 + r] = v.w;
    }
    __syncthreads();
    float* WT = ws + WS_WT;
#pragma unroll
    for (int p = 0; p < 4; ++p) {
      int c = p*16 + (t >> 4), r4 = t & 15;
      float4 v = make_float4(ts[c*65 + r4*4], ts[c*65 + r4*4 + 1],
                             ts[c*65 + r4*4 + 2], ts[c*65 + r4*4 + 3]);
      *(float4*)(WT + (size_t)(c0+c)*768 + r0 + r4*4) = v;
    }
  } else if (bid == 48) {
    // ---- pair selection, class ids, Wk, cm, inv_den ----
    float* csh = sm;                  // 64
    float* cls = sm + 64;             // 46
    float* wsh = sm + 112;            // 46
    float* den = sm + 160;            // 1
    float* Wk  = sm + 192;            // 2944 -> ends 3136
    int* scan = (int*)(sm + 3200);    // 256
    int* l0   = (int*)(sm + 3456);    // 64
    int* l1   = (int*)(sm + 3520);    // 64
    int* seli = (int*)(sm + 3584);    // 512
    int* selj = (int*)(sm + 4096);    // 512
    if (t < 64) { l0[t] = labels0[t]; l1[t] = labels1[t]; csh[t] = 0.f; }
    if (t < KC_) cls[t] = 0.f;
    if (t == 0) den[0] = 0.f;
    for (int i = t; i < 2944; i += 256) Wk[i] = 0.f;
    __syncthreads();
    unsigned bits = 0; int c = 0;
    for (int u = 0; u < 16; ++u) {    // contiguous 16-chunk keeps row-major order
      int idx = t*16 + u;
      if (l1[idx>>6] == l1[idx&63]) { bits |= 1u<<u; ++c; }
    }
    scan[t] = c; __syncthreads();
    for (int off = 1; off < 256; off <<= 1) {
      int v = (t >= off) ? scan[t-off] : 0;
      __syncthreads();
      scan[t] += v;
      __syncthreads();
    }
    const int total = scan[255];
    int rank = scan[t] - c;           // exclusive prefix
    for (int p = t; p < P_; p += 256)
      if (p >= total) { seli[p] = 0; selj[p] = 0; }   // fill_value=0
    for (int u = 0; u < 16; ++u) {
      if (bits & (1u<<u)) {
        if (rank < P_) { int idx = t*16+u; seli[rank] = idx>>6; selj[rank] = idx&63; }
        ++rank;
      }
    }
    __syncthreads();
    int ii[2], yy[2]; float vv[2];
#pragma unroll
    for (int r = 0; r < 2; ++r) {
      int p = t + r*256;
      int i = seli[p], j = selj[p];
      atomicAdd(&csh[j], 1.0f);       // multiplicity incl. padding pairs
      int la = l0[i], lb = l0[j];
      int y;
      if (la == lb) y = 0;
      else {
        int lo = la < lb ? la : lb, hi = la < lb ? lb : la;
        y = 1 + lo*9 - (lo*(lo-1))/2 + (hi-lo-1);
      }
      float v = (p < total) ? 1.f : 0.f;
      if (v > 0.f) atomicAdd(&cls[y], 1.f);
      ii[r] = i; yy[r] = y; vv[r] = v;
    }
    __syncthreads();
    if (t < KC_) {
      float cv = cls[t];
      wsh[t] = cv > 0.f ? 1.0f/cv : 0.f;
      if (cv > 0.f) atomicAdd(den, 1.0f);   // sum(wy) == #present classes
    }
    __syncthreads();
#pragma unroll
    for (int r = 0; r < 2; ++r)
      if (vv[r] > 0.f) atomicAdd(&Wk[ii[r]*KC_ + yy[r]], wsh[yy[r]]);
    __syncthreads();
    if (t < 64) ws[WS_CM + t] = csh[t];
    for (int i = t; i < 2944; i += 256) ws[WS_WK + i] = Wk[i];
    if (t == 0) ws[WS_INVDEN] = 1.0f / den[0];
  } else if (bid < 95) {
    // ---- M[k,:] = hw[k,:] @ Wout  and  c[k] ----
    int k = bid - 49;
    float* hwsh = sm;                 // 256
    float* redA = sm + 256;           // 256
    float* redB = sm + 512;           // 256
    hwsh[t] = hw[k*E_ + t];
    __syncthreads();
    float a0 = 0.f;
#pragma unroll 8
    for (int e = 0; e < E_; ++e) a0 = fmaf(hwsh[e], wout[e*E_ + t], a0);
    ws[WS_M + k*E_ + t] = a0;
    redA[t] = hwsh[t];
    redB[t] = hwsh[t]*bout[t];
    __syncthreads();
    for (int off = 128; off > 0; off >>= 1) {
      if (t < off) { redA[t] += redA[t+off]; redB[t] += redB[t+off]; }
      __syncthreads();
    }
    if (t == 0) {
      float sfw = 0.f;
      for (int s = 0; s < S_; ++s) sfw += fw[s];
      ws[WS_C + k] = fbi[0]*redA[0] + sfw*redB[0] + hb[k];
    }
  } else {
    if (t == 0) out[0] = 0.f;
  }
}

// ============ K1: QKV projection, W from global WT (VMEM), X from LDS ======
// grid (6 out-chunks of 128, 64 b) x 256 threads; thread tile 4 out x 4 s
__global__ __launch_bounds__(256) void k_proj(
    const float* __restrict__ feat, const float* __restrict__ bias,
    float* __restrict__ ws) {
  const int cc = blockIdx.x, b = blockIdx.y, t = threadIdx.x;
  __shared__ float xs[E_*S_];
  float4* xs4 = (float4*)xs;
  const float4* fb4 = (const float4*)(feat + (size_t)b*(E_*S_));
#pragma unroll
  for (int i = 0; i < 8; ++i) xs4[i*256 + t] = fb4[i*256 + t];
  __syncthreads();
  const int to = t & 31, ts = t >> 5;
  const float4* WT4 = (const float4*)(ws + WS_WT);
  const int wi = cc*32 + to;
  float acc[4][4];
#pragma unroll
  for (int o = 0; o < 4; ++o)
#pragma unroll
    for (int si = 0; si < 4; ++si) acc[o][si] = 0.f;
#pragma unroll 4
  for (int e = 0; e < E_; ++e) {
    float4 wv4 = WT4[e*192 + wi];
    float4 x4  = xs4[e*8 + ts];
    float wv[4] = {wv4.x, wv4.y, wv4.z, wv4.w};
    float xv[4] = {x4.x, x4.y, x4.z, x4.w};
#pragma unroll
    for (int o = 0; o < 4; ++o)
#pragma unroll
      for (int si = 0; si < 4; ++si)
        acc[o][si] = fmaf(wv[o], xv[si], acc[o][si]);
  }
  const int out0 = cc*128 + to*4;
  float4 bb = *(const float4*)(bias + out0);
  const int r = out0 >> 8, e_in = out0 & 255;
  float* dst = ws + WS_QKV + (size_t)r*QKV_N + (size_t)b*(S_*E_) + e_in;
#pragma unroll
  for (int si = 0; si < 4; ++si) {
    int s = ts*4 + si;
    *(float4*)(dst + s*E_) = make_float4(acc[0][si]+bb.x, acc[1][si]+bb.y,
                                         acc[2][si]+bb.z, acc[3][si]+bb.w);
  }
}

// ============ K2: weighted attention per (s,h); writes exclusive O_part ====
__global__ __launch_bounds__(256) void k_attn(
    float* __restrict__ ws, const float* __restrict__ fw) {
  const int s = blockIdx.x >> 4, h = blockIdx.x & 15;
  const int t = threadIdx.x;
  __shared__ float qT[16*68], kT[16*68], vs[64*20];
  __shared__ float sc[64*68], pT[64*68], red[4*64*20], cm[64];
  const float* qkv = ws + WS_QKV;
  const int a = t >> 2, dq = t & 3;
  {
    size_t off = (size_t)a*(S_*E_) + (size_t)s*E_ + h*16 + dq*4;
    float4 q4 = *(const float4*)(qkv + off);
    float4 k4 = *(const float4*)(qkv + QKV_N + off);
    float4 v4 = *(const float4*)(qkv + 2*(size_t)QKV_N + off);
    qT[(dq*4+0)*68 + a] = q4.x; qT[(dq*4+1)*68 + a] = q4.y;
    qT[(dq*4+2)*68 + a] = q4.z; qT[(dq*4+3)*68 + a] = q4.w;
    kT[(dq*4+0)*68 + a] = k4.x; kT[(dq*4+1)*68 + a] = k4.y;
    kT[(dq*4+2)*68 + a] = k4.z; kT[(dq*4+3)*68 + a] = k4.w;
    *(float4*)(vs + a*20 + dq*4) = v4;
  }
  if (t < 64) cm[t] = ws[WS_CM + t];
  __syncthreads();
  // ---- scores: 4x4 register outer product ----
  const int ta = t & 15, tb = t >> 4;
  float sa[4][4];
#pragma unroll
  for (int r = 0; r < 4; ++r)
#pragma unroll
    for (int c = 0; c < 4; ++c) sa[r][c] = 0.f;
#pragma unroll
  for (int d = 0; d < 16; ++d) {
    float4 qv = *(float4*)(qT + d*68 + ta*4);
    float4 kv = *(float4*)(kT + d*68 + tb*4);
    float qr[4] = {qv.x,qv.y,qv.z,qv.w};
    float kc[4] = {kv.x,kv.y,kv.z,kv.w};
#pragma unroll
    for (int r = 0; r < 4; ++r)
#pragma unroll
      for (int c = 0; c < 4; ++c) sa[r][c] = fmaf(qr[r], kc[c], sa[r][c]);
  }
#pragma unroll
  for (int r = 0; r < 4; ++r)
    *(float4*)(sc + (ta*4+r)*68 + tb*4) =
        make_float4(sa[r][0]*0.25f, sa[r][1]*0.25f, sa[r][2]*0.25f, sa[r][3]*0.25f);
  __syncthreads();
  // ---- weighted softmax row a; thread covers b = dq*16..dq*16+15 ----
  float pv[16], cmv[16];
#pragma unroll
  for (int i4 = 0; i4 < 4; ++i4) {
    float4 v = *(float4*)(sc + a*68 + dq*16 + i4*4);
    pv[i4*4+0] = v.x; pv[i4*4+1] = v.y; pv[i4*4+2] = v.z; pv[i4*4+3] = v.w;
  }
#pragma unroll
  for (int i = 0; i < 16; ++i) cmv[i] = cm[dq*16 + i];
  float Mx = -1e30f;
#pragma unroll
  for (int i = 0; i < 16; ++i) if (cmv[i] > 0.f) Mx = fmaxf(Mx, pv[i]);
  Mx = fmaxf(Mx, __shfl_xor(Mx, 1));
  Mx = fmaxf(Mx, __shfl_xor(Mx, 2));
  float z = 0.f;
#pragma unroll
  for (int i = 0; i < 16; ++i) {
    float e = (cmv[i] > 0.f) ? cmv[i]*__expf(pv[i]-Mx) : 0.f;
    pv[i] = e; z += e;
  }
  z += __shfl_xor(z, 1);
  z += __shfl_xor(z, 2);
  float rz = 1.0f / z;
#pragma unroll
  for (int i = 0; i < 16; ++i) pT[(dq*16+i)*68 + a] = pv[i]*rz;
  __syncthreads();
  // ---- PV: split b over 4 waves, 4a x 4d register tile ----
  const int g = t >> 6, td = (t >> 4) & 3, ta2 = t & 15;
  float o[4][4];
#pragma unroll
  for (int r = 0; r < 4; ++r)
#pragma unroll
    for (int c = 0; c < 4; ++c) o[r][c] = 0.f;
#pragma unroll
  for (int i = 0; i < 16; ++i) {
    int bb = g*16 + i;
    float4 p4 = *(float4*)(pT + bb*68 + ta2*4);
    float4 v4 = *(float4*)(vs + bb*20 + td*4);
    float pr[4] = {p4.x,p4.y,p4.z,p4.w};
    float vc[4] = {v4.x,v4.y,v4.z,v4.w};
#pragma unroll
    for (int r = 0; r < 4; ++r)
#pragma unroll
      for (int c = 0; c < 4; ++c) o[r][c] = fmaf(pr[r], vc[c], o[r][c]);
  }
#pragma unroll
  for (int r = 0; r < 4; ++r)
    *(float4*)(red + g*1280 + (ta2*4+r)*20 + td*4) =
        make_float4(o[r][0], o[r][1], o[r][2], o[r][3]);
  __syncthreads();
  // ---- reduce over g, scale by fw[s], store exclusive O_part slice ----
  const float fwS = fw[s];
  float4 osum = make_float4(0.f, 0.f, 0.f, 0.f);
#pragma unroll
  for (int g2 = 0; g2 < 4; ++g2) {
    float4 v = *(float4*)(red + g2*1280 + a*20 + dq*4);
    osum.x += v.x; osum.y += v.y; osum.z += v.z; osum.w += v.w;
  }
  // O_part[s][h][a][d]: block-exclusive, wave stores are 1KB contiguous
  float* dst = ws + WS_OPART + (size_t)s*(H_*B_*16) + h*(B_*16) + a*16 + dq*4;
  *(float4*)dst = make_float4(fwS*osum.x, fwS*osum.y, fwS*osum.z, fwS*osum.w);
}

// ============ K3: reduce O_part + logits + lse + weighted-CE per row =======
__global__ __launch_bounds__(256) void k_final(
    const float* __restrict__ ws, float* __restrict__ out) {
  const int aa = blockIdx.x, t = threadIdx.x;
  __shared__ float oh[256], lg[64];
  {
    // e = t; O_hat[aa][e] = sum_s O_part[s][e>>4][aa][e&15]
    const float* op = ws + WS_OPART + (t>>4)*(B_*16) + aa*16 + (t&15);
    float acc = 0.f;
#pragma unroll
    for (int s = 0; s < S_; ++s) acc += op[(size_t)s*(H_*B_*16)];
    oh[t] = acc;
  }
  __syncthreads();
  const int k = t >> 2, q = t & 3;
  if (k < KC_) {
    float lv = 0.f;
    const float4* M4 = (const float4*)(ws + WS_M + k*E_ + q*64);
    const float4* o4 = (const float4*)(oh + q*64);
#pragma unroll
    for (int j = 0; j < 16; ++j) {
      float4 m = M4[j], o = o4[j];
      lv = fmaf(m.x, o.x, lv); lv = fmaf(m.y, o.y, lv);
      lv = fmaf(m.z, o.z, lv); lv = fmaf(m.w, o.w, lv);
    }
    lv += __shfl_xor(lv, 1);
    lv += __shfl_xor(lv, 2);
    if (q == 0) lg[k] = lv + ws[WS_C + k];
  }
  __syncthreads();
  if (t < 64) {
    float x = (t < KC_) ? lg[t] : -1e30f;
    float Mx = x;
#pragma unroll
    for (int off = 1; off < 64; off <<= 1) Mx = fmaxf(Mx, __shfl_xor(Mx, off));
    float z = (t < KC_) ? __expf(x - Mx) : 0.f;
#pragma unroll
    for (int off = 1; off < 64; off <<= 1) z += __shfl_xor(z, off);
    float lse = Mx + __logf(z);
    float term = (t < KC_) ? ws[WS_WK + aa*KC_ + t] * (lse - x) : 0.f;
#pragma unroll
    for (int off = 1; off < 64; off <<= 1) term += __shfl_xor(term, off);
    if (t == 0) atomicAdd(out, term * ws[WS_INVDEN]);
  }
}

extern "C" void kernel_launch(void* const* d_in, const int* in_sizes, int n_in,
                              void* d_out, int out_size, void* d_ws, size_t ws_size,
                              hipStream_t stream) {
  const float* feat    = (const float*)d_in[0];
  const int*   labels0 = (const int*)d_in[1];
  const int*   labels1 = (const int*)d_in[2];
  const float* ipw     = (const float*)d_in[3];
  const float* ipb     = (const float*)d_in[4];
  const float* opw     = (const float*)d_in[5];
  const float* opb     = (const float*)d_in[6];
  const float* fw      = (const float*)d_in[7];
  const float* fbi     = (const float*)d_in[8];
  const float* hw      = (const float*)d_in[9];
  const float* hb      = (const float*)d_in[10];
  float* out = (float*)d_out;
  float* ws  = (float*)d_ws;

  k_prep<<<96, 256, 0, stream>>>(ipw, labels0, labels1, opw, opb, fw, fbi,
                                 hw, hb, ws, out);
  k_proj<<<dim3(6, 64), 256, 0, stream>>>(feat, ipb, ws);
  k_attn<<<512, 256, 0, stream>>>(ws, fw);
  k_final<<<64, 256, 0, stream>>>(ws, out);
}